// Round 11
// baseline (1251.153 us; speedup 1.0000x reference)
//
#include <hip/hip_runtime.h>

// Problem constants
#define B_   16
#define T_   16
#define H_   161
#define W_   181
#define HW_  (H_*W_)     // 29141
#define C_   3
#define F_   21
#define F4_  84
#define TSX  32          // tile width
#define TSY  8           // tile height (256 px per block)
#define TPX  34          // tile + halo
#define TPY  10
#define NPOS (TPX*TPY)   // 340
#define NTAP 9
#define MT_  6           // m-tiles of 16 -> 96 gate rows (m = f*4+gate)
#define ROWB4 64         // packed kernel: 4 slots x 16B per position (hi-only B)
#define ROWBF 128        // fallback kernel: 8 slots x 16B (hi/lo B)
// ci map: 0..20 = h (bf16-hi), 21..23 = pad, 24..26 = x_hi, 27..29 = x_lo, 30..31 = pad.
// A weights: ci 27..29 carry wx duplicated (both hi and lo fragments) so the
// x path is EXACT: (wx_hi+wx_lo)*(x_hi+x_lo). Only h is truncated to bf16 (2^-9).
#define GH_ ((size_t)B_ * 3 * HW_)   // uint4 elements per gh buffer (hi plane only)

typedef short bf16x8 __attribute__((ext_vector_type(8)));
typedef float f32x4  __attribute__((ext_vector_type(4)));

__device__ __forceinline__ float hsig(float x) {
  return fminf(fmaxf(0.2f * x + 0.5f, 0.0f), 1.0f);
}

__device__ __forceinline__ float fast_tanh(float x) {
  float ax = fabsf(x);
  float t = __expf(-2.0f * ax);
  float r = (1.0f - t) * __builtin_amdgcn_rcpf(1.0f + t);
  return copysignf(r, x);
}

// round-to-nearest-even fp32 -> bf16 bits
__device__ __forceinline__ unsigned short bf16r(float x) {
  unsigned u = __float_as_uint(x);
  return (unsigned short)((u + 0x7FFFu + ((u >> 16) & 1u)) >> 16);
}
__device__ __forceinline__ void bsplit(float v, unsigned short& hi, unsigned short& lo) {
  hi = bf16r(v);
  float hf = __uint_as_float((unsigned)hi << 16);
  lo = bf16r(v - hf);
}

// A-fragment pack: Af[tap][mt][hl][lane] (uint4 = 8 bf16). HW-verified r2.
// mfma_f32_16x16x32_bf16 A layout: row m = lane&15, k = (lane>>4)*8 + j.
// m = f*4 + gate; oc = gate*21 + f (Keras i,f,c,o).
// hl=0: bf16(w); hl=1: bf16(w - bf16(w)). x weights duplicated at ci 27..29.
__global__ void prep_kernel(const float* __restrict__ k,
                            const float* __restrict__ rk,
                            const float* __restrict__ bias,
                            unsigned short* __restrict__ Af,
                            float* __restrict__ bias4) {
  int i = blockIdx.x * 256 + threadIdx.x;
  if (i < NTAP * MT_ * 2 * 64 * 8) {
    int j    = i & 7;
    int lane = (i >> 3) & 63;
    int hl   = (i >> 9) & 1;
    int mtp  = i >> 10;          // tap*MT_ + mt
    int mt   = mtp % MT_;
    int tap  = mtp / MT_;
    int m    = mt * 16 + (lane & 15);
    int ci   = (lane >> 4) * 8 + j;
    int f    = m >> 2, gate = m & 3;
    float w = 0.0f;
    if (f < F_) {
      int oc = gate * F_ + f;
      if (ci < F_)                  w = rk[(tap * F_ + ci) * F4_ + oc];        // h
      else if (ci >= 24 && ci < 27) w = k[(tap * C_ + (ci - 24)) * F4_ + oc];  // x_hi slot
      else if (ci >= 27 && ci < 30) w = k[(tap * C_ + (ci - 27)) * F4_ + oc];  // x_lo slot (dup wx)
    }
    unsigned short hb = bf16r(w);
    unsigned short outv;
    if (hl == 0) outv = hb;
    else {
      float hf = __uint_as_float((unsigned)hb << 16);
      outv = bf16r(w - hf);
    }
    Af[i] = outv;
  }
  if (i < 96) {   // bias4[f][gate], f padded to 24
    int f = i >> 2, gate = i & 3;
    bias4[i] = (f < F_) ? bias[gate * F_ + f] : 0.0f;
  }
}

// ---------------- packed-h 1-step kernel (hi-only B, A-pipelined) ----------------
// grid (6,21,16), block 768 (12 waves): wvm = wv>>2 (0..2) owns m-tiles
// {2wvm,2wvm+1}; wvn = wv&3 owns rows {2wvn,2wvn+1} (4 n-tiles).
// Round 11: A-fragment loads double-buffered across tap iterations (preload
// tap 0; iteration `tap` issues tap+1's 4x16B loads before its MFMA cluster)
// -> the ~200cyc L2 latency of A hides under a full iteration of MFMA+ds_read.
// cpre removed (r10: neutral) to keep regs ~80 <= 85 cap.
__global__ void __launch_bounds__(768, 6) step_kernel_p(
    const float* __restrict__ x,        // (B,T,H,W,C) fp32
    const uint4* __restrict__ Af,       // [9][6][2][64] uint4
    const float* __restrict__ bias4,    // [24][4]
    const uint4* __restrict__ g_in,     // h bf16-hi plane (prev step)
    uint4* __restrict__ g_out,          // h bf16-hi plane (this step)
    float* __restrict__ c_buf,          // (B,21,HW) fp32 in-place
    const float* __restrict__ mask,     // (H,W,1)
    float* __restrict__ out,            // (B,H,W,21) fp32, last step only
    int t, int first, int last) {
  __shared__ uint4 tileQ[NPOS * 4];     // 21760 B
  __shared__ uint4 bounceQ[768];        // 12288 B (disjoint -> no post-MFMA barrier)
  unsigned char* tile = (unsigned char*)tileQ;
  unsigned short* bh16 = (unsigned short*)bounceQ;   // [256][24] bf16-hi bounce

  int b   = blockIdx.z;
  int by0 = blockIdx.y * TSY;
  int bx0 = blockIdx.x * TSX;
  int tid = threadIdx.x;

  // ---- stage tile: slots 0..2 = h groups (raw 16B copies); slot 3 = x hi+lo ----
  for (int i = tid; i < 4 * NPOS; i += 768) {
    int slot = i / NPOS;
    int pos  = i - slot * NPOS;
    int py = pos / TPX, px = pos - py * TPX;
    int gy = by0 - 1 + py, gx = bx0 - 1 + px;
    bool inb = (unsigned)gy < (unsigned)H_ && (unsigned)gx < (unsigned)W_;
    int sw = pos & 3;
    if (slot < 3) {
      uint4 v = {0u, 0u, 0u, 0u};
      if (!first && inb)
        v = g_in[(size_t)(b * 3 + slot) * HW_ + gy * W_ + gx];
      *(uint4*)&tile[pos * ROWB4 + ((slot ^ sw) * 16)] = v;
    } else {
      float x0 = 0.f, x1 = 0.f, x2 = 0.f;
      if (inb) {
        const float* xp = x + (((size_t)(b * T_ + t) * H_ + gy) * W_ + gx) * C_;
        x0 = xp[0]; x1 = xp[1]; x2 = xp[2];
      }
      unsigned short h0, h1, h2, l0, l1, l2;
      bsplit(x0, h0, l0); bsplit(x1, h1, l1); bsplit(x2, h2, l2);
      // k-slots 24..31 within this 16B: [x0h,x1h,x2h, x0l,x1l,x2l, 0,0]
      uint4 v;
      v.x = (unsigned)h0 | ((unsigned)h1 << 16);
      v.y = (unsigned)h2 | ((unsigned)l0 << 16);
      v.z = (unsigned)l1 | ((unsigned)l2 << 16);
      v.w = 0u;
      *(uint4*)&tile[pos * ROWB4 + ((3 ^ sw) * 16)] = v;
    }
  }
  __syncthreads();

  int lane = tid & 63;
  int wv   = tid >> 6;     // 0..11
  int wvm  = wv >> 2;      // m-group 0..2 -> m-tiles {2wvm, 2wvm+1}
  int wvn  = wv & 3;       // row pair 0..3 -> rows {2wvn, 2wvn+1}
  int ln15 = lane & 15;
  int lg   = lane >> 4;

  f32x4 acc[2][4];
#pragma unroll
  for (int mt = 0; mt < 2; ++mt)
#pragma unroll
    for (int nt = 0; nt < 4; ++nt)
      acc[mt][nt] = (f32x4){0.f, 0.f, 0.f, 0.f};

  // A-fragment double buffer: abase[tap*768 + {0,64,128,192}]
  const uint4* abase = Af + (size_t)(wvm * 2) * 128 + lane;
  uint4 na0 = abase[0];
  uint4 na1 = abase[64];
  uint4 na2 = abase[128];
  uint4 na3 = abase[192];

#pragma unroll 1
  for (int tap = 0; tap < NTAP; ++tap) {
    int ky = tap / 3;
    int kx = tap - 3 * ky;

    bf16x8 ah0 = __builtin_bit_cast(bf16x8, na0);
    bf16x8 al0 = __builtin_bit_cast(bf16x8, na1);
    bf16x8 ah1 = __builtin_bit_cast(bf16x8, na2);
    bf16x8 al1 = __builtin_bit_cast(bf16x8, na3);

    if (tap < NTAP - 1) {       // issue next tap's A loads BEFORE this tap's MFMAs
      const uint4* ap = abase + (size_t)(tap + 1) * 768;
      na0 = ap[0];
      na1 = ap[64];
      na2 = ap[128];
      na3 = ap[192];
    }

#pragma unroll
    for (int nt = 0; nt < 4; ++nt) {
      int pos = (wvn * 2 + (nt >> 1) + ky) * TPX + (nt & 1) * 16 + ln15 + kx;
      int sw  = pos & 3;
      uint4 hv = *(const uint4*)&tile[pos * ROWB4 + ((lg ^ sw) * 16)];
      bf16x8 bh = __builtin_bit_cast(bf16x8, hv);
      acc[0][nt] = __builtin_amdgcn_mfma_f32_16x16x32_bf16(ah0, bh, acc[0][nt], 0, 0, 0);
      acc[0][nt] = __builtin_amdgcn_mfma_f32_16x16x32_bf16(al0, bh, acc[0][nt], 0, 0, 0);
      acc[1][nt] = __builtin_amdgcn_mfma_f32_16x16x32_bf16(ah1, bh, acc[1][nt], 0, 0, 0);
      acc[1][nt] = __builtin_amdgcn_mfma_f32_16x16x32_bf16(al1, bh, acc[1][nt], 0, 0, 0);
    }
  }

  // NO barrier here: bounce is disjoint from tile; each wave proceeds into its
  // epilogue immediately, overlapping other waves' MFMA phase.

  // ---- lane-local LSTM epilogue; h -> bounce LDS as bf16-hi ----
#pragma unroll
  for (int mt = 0; mt < 2; ++mt) {
    int f = (wvm * 2 + mt) * 4 + lg;    // 0..23 (21..23 -> exact zero h)
    float4 bb = ((const float4*)bias4)[f];
#pragma unroll
    for (int nt = 0; nt < 4; ++nt) {
      int py = wvn * 2 + (nt >> 1);
      int px = (nt & 1) * 16 + ln15;
      int gy = by0 + py, gx = bx0 + px;
      if (gy < H_ && gx < W_) {
        int    pixL = py * TSX + px;
        size_t gpix = (size_t)gy * W_ + gx;
        float zi = acc[mt][nt][0] + bb.x;
        float zf = acc[mt][nt][1] + bb.y;
        float zc = acc[mt][nt][2] + bb.z;
        float zo = acc[mt][nt][3] + bb.w;
        float ig = hsig(zi);
        float fg = hsig(zf);
        float gg = fast_tanh(zc);
        float og = hsig(zo);
        float cp = (first || f >= F_) ? 0.0f
                                      : c_buf[((size_t)b * F_ + f) * HW_ + gpix];
        float cn = fg * cp + ig * gg;
        float hn = og * fast_tanh(cn);
        if (f < F_ && !last) c_buf[((size_t)b * F_ + f) * HW_ + gpix] = cn;
        if (last) {
          if (f < F_)
            out[((size_t)(b * H_ + gy) * W_ + gx) * F_ + f] = hn * mask[gpix];
        } else {
          bh16[pixL * 24 + f] = bf16r(hn);
        }
      }
    }
  }

  if (last) return;
  __syncthreads();

  // ---- pack bounce -> g_out (coalesced 16B stores), 1 iter/thread ----
  for (int i = tid; i < 256 * 3; i += 768) {
    int g    = i >> 8;
    int pixL = i & 255;
    int py = pixL >> 5, px = pixL & 31;
    int gy = by0 + py, gx = bx0 + px;
    if (gy < H_ && gx < W_) {
      uint4 v = *(const uint4*)(bh16 + pixL * 24 + g * 8);
      g_out[(size_t)(b * 3 + g) * HW_ + (size_t)gy * W_ + gx] = v;
    }
  }
}

// ---------------- fallback path (round-2 proven structure, ~78 MB ws) ----------------
// Consumes the same Af (x_lo k-slots stage as zero; its ah*bl term recovers x_lo).
__global__ void __launch_bounds__(256, 3) step_kernel_f(
    const float* __restrict__ x,
    const uint4* __restrict__ Af,
    const float* __restrict__ bias4,
    const float* __restrict__ h_in,     // (B,F,HW) fp32
    float* __restrict__ h_out,          // (B,F,HW) fp32
    float* __restrict__ c_buf,
    const float* __restrict__ mask,
    float* __restrict__ out,
    int t, int first, int last) {
  __shared__ uint4 tileQ[NPOS * 8];
  unsigned char* tile = (unsigned char*)tileQ;

  int b   = blockIdx.z;
  int by0 = blockIdx.y * TSY;
  int bx0 = blockIdx.x * TSX;
  int tid = threadIdx.x;

  for (int i = tid; i < 32 * NPOS; i += 256) {
    int ci  = i / NPOS;
    int pos = i - ci * NPOS;
    int py = pos / TPX, px = pos - py * TPX;
    int gy = by0 - 1 + py, gx = bx0 - 1 + px;
    float v = 0.0f;
    if ((unsigned)gy < (unsigned)H_ && (unsigned)gx < (unsigned)W_) {
      if (ci < F_) {
        if (!first) v = h_in[(size_t)(b * F_ + ci) * HW_ + gy * W_ + gx];
      } else if (ci >= 24 && ci < 27) {
        v = x[(((size_t)(b * T_ + t) * H_ + gy) * W_ + gx) * C_ + (ci - 24)];
      }
    }
    unsigned short hb, lb;
    bsplit(v, hb, lb);
    int g  = ci >> 3, e = ci & 7, sw = pos & 7;
    *(unsigned short*)&tile[pos * ROWBF + (((g * 2 + 0) ^ sw) * 16) + e * 2] = hb;
    *(unsigned short*)&tile[pos * ROWBF + (((g * 2 + 1) ^ sw) * 16) + e * 2] = lb;
  }
  __syncthreads();

  int lane = tid & 63;
  int wv   = tid >> 6;
  int ln15 = lane & 15;
  int lg   = lane >> 4;

  f32x4 acc[MT_][4];
#pragma unroll
  for (int mt = 0; mt < MT_; ++mt)
#pragma unroll
    for (int nt = 0; nt < 4; ++nt)
      acc[mt][nt] = (f32x4){0.f, 0.f, 0.f, 0.f};

#pragma unroll 1
  for (int tap = 0; tap < NTAP; ++tap) {
    int ky = tap / 3;
    int kx = tap - 3 * ky;

    bf16x8 bh[4], bl[4];
#pragma unroll
    for (int nt = 0; nt < 4; ++nt) {
      int pos = (wv * 2 + (nt >> 1) + ky) * TPX + (nt & 1) * 16 + ln15 + kx;
      int sw  = pos & 7;
      uint4 hv = *(const uint4*)&tile[pos * ROWBF + (((lg * 2 + 0) ^ sw) * 16)];
      uint4 lv = *(const uint4*)&tile[pos * ROWBF + (((lg * 2 + 1) ^ sw) * 16)];
      bh[nt] = __builtin_bit_cast(bf16x8, hv);
      bl[nt] = __builtin_bit_cast(bf16x8, lv);
    }

#pragma unroll
    for (int mt = 0; mt < MT_; ++mt) {
      const uint4* ap = Af + (size_t)((tap * MT_ + mt) * 2) * 64 + lane;
      bf16x8 ah = __builtin_bit_cast(bf16x8, ap[0]);
      bf16x8 al = __builtin_bit_cast(bf16x8, ap[64]);
#pragma unroll
      for (int nt = 0; nt < 4; ++nt) {
        acc[mt][nt] = __builtin_amdgcn_mfma_f32_16x16x32_bf16(ah, bh[nt], acc[mt][nt], 0, 0, 0);
        acc[mt][nt] = __builtin_amdgcn_mfma_f32_16x16x32_bf16(ah, bl[nt], acc[mt][nt], 0, 0, 0);
        acc[mt][nt] = __builtin_amdgcn_mfma_f32_16x16x32_bf16(al, bh[nt], acc[mt][nt], 0, 0, 0);
      }
    }
  }

#pragma unroll
  for (int mt = 0; mt < MT_; ++mt) {
    int f = mt * 4 + lg;
    if (f < F_) {
      float4 bb = ((const float4*)bias4)[f];
#pragma unroll
      for (int nt = 0; nt < 4; ++nt) {
        int gy = by0 + wv * 2 + (nt >> 1);
        int gx = bx0 + (nt & 1) * 16 + ln15;
        if (gy < H_ && gx < W_) {
          size_t idx = ((size_t)b * F_ + f) * HW_ + (size_t)gy * W_ + gx;
          float zi = acc[mt][nt][0] + bb.x;
          float zf = acc[mt][nt][1] + bb.y;
          float zc = acc[mt][nt][2] + bb.z;
          float zo = acc[mt][nt][3] + bb.w;
          float ig = hsig(zi);
          float fg = hsig(zf);
          float gg = fast_tanh(zc);
          float og = hsig(zo);
          float cp = first ? 0.0f : c_buf[idx];
          float cn = fg * cp + ig * gg;
          float hn = og * fast_tanh(cn);
          c_buf[idx] = cn;
          if (!last) h_out[idx] = hn;
          else {
            out[((size_t)(b * H_ + gy) * W_ + gx) * F_ + f] =
                hn * mask[(size_t)gy * W_ + gx];
          }
        }
      }
    }
  }
}

extern "C" void kernel_launch(void* const* d_in, const int* in_sizes, int n_in,
                              void* d_out, int out_size, void* d_ws, size_t ws_size,
                              hipStream_t stream) {
  const float* x  = (const float*)d_in[0];
  const float* k  = (const float*)d_in[1];
  const float* rk = (const float*)d_in[2];
  const float* bs = (const float*)d_in[3];
  const float* mk = (const float*)d_in[4];
  float* outF = (float*)d_out;

  char* ws = (char*)d_ws;
  unsigned short* Af = (unsigned short*)ws;          // 110592 B
  float* bias4 = (float*)(ws + 110592);              // 384 B
  size_t off = (size_t)((110592 + 384 + 255) & ~255);
  size_t HWF = (size_t)B_ * H_ * W_ * F_;

  prep_kernel<<<dim3((NTAP * MT_ * 2 * 64 * 8 + 255) / 256), 256, 0, stream>>>(
      k, rk, bs, Af, bias4);

  dim3 grid((W_ + TSX - 1) / TSX, (H_ + TSY - 1) / TSY, B_);  // (6, 21, 16)

  size_t need_packed = off + (size_t)2 * GH_ * 16 + HWF * 4;  // ~84 MB

  if (ws_size >= need_packed) {
    // packed-h path: ghA/ghB = bf16-hi h planes, c fp32
    uint4* ghA = (uint4*)(ws + off);
    uint4* ghB = ghA + GH_;
    float* cB  = (float*)(ghB + GH_);
    for (int t = 0; t < T_; ++t) {
      const uint4* gin = (t & 1) ? ghB : ghA;
      uint4* gout      = (t & 1) ? ghA : ghB;
      step_kernel_p<<<grid, 768, 0, stream>>>(x, (const uint4*)Af, bias4, gin, gout,
                                              cB, mk, outF, t,
                                              (t == 0) ? 1 : 0, (t == T_ - 1) ? 1 : 0);
    }
  } else {
    // fallback (round-2 proven): fp32 h ping-pong via ws + outF, ~78.4 MB
    float* hA = (float*)(ws + off);
    float* cB = hA + HWF;
    for (int t = 0; t < T_; ++t) {
      const float* hi = (t & 1) ? hA : outF;
      float* ho       = (t & 1) ? outF : hA;
      step_kernel_f<<<grid, 256, 0, stream>>>(x, (const uint4*)Af, bias4, hi, ho,
                                              cB, mk, outF, t,
                                              (t == 0) ? 1 : 0, (t == T_ - 1) ? 1 : 0);
    }
  }
}

// Round 12
// 1215.229 us; speedup vs baseline: 1.0296x; 1.0296x over previous
//
#include <hip/hip_runtime.h>

// Problem constants
#define B_   16
#define T_   16
#define H_   161
#define W_   181
#define HW_  (H_*W_)     // 29141
#define C_   3
#define F_   21
#define F4_  84
#define TSX  32          // tile width
#define TSY  8           // tile height (256 px per block)
#define TPX  34          // tile + halo
#define TPY  10
#define NPOS (TPX*TPY)   // 340
#define NTAP 9
#define MT_  6           // m-tiles of 16 -> 96 gate rows (m = f*4+gate)
#define ROWB5 80         // packed kernel: 5x16B per position, LINEAR (no swizzle).
                         // pos stride = 80B = 20 banks -> 2-way aliasing = free.
#define ROWBF 128        // fallback kernel: 8 slots x 16B (hi/lo B, swizzled)
// ci map: 0..20 = h (bf16-hi), 21..23 = pad, 24..26 = x_hi, 27..29 = x_lo, 30..31 = pad.
// A weights: ci 27..29 carry wx duplicated (both hi and lo fragments) so the
// x path is EXACT: (wx_hi+wx_lo)*(x_hi+x_lo). Only h is truncated to bf16 (2^-9).
#define GH_ ((size_t)B_ * 3 * HW_)   // uint4 elements per gh buffer (hi plane only)

typedef short bf16x8 __attribute__((ext_vector_type(8)));
typedef float f32x4  __attribute__((ext_vector_type(4)));

__device__ __forceinline__ float hsig(float x) {
  return fminf(fmaxf(0.2f * x + 0.5f, 0.0f), 1.0f);
}

__device__ __forceinline__ float fast_tanh(float x) {
  float ax = fabsf(x);
  float t = __expf(-2.0f * ax);
  float r = (1.0f - t) * __builtin_amdgcn_rcpf(1.0f + t);
  return copysignf(r, x);
}

// round-to-nearest-even fp32 -> bf16 bits
__device__ __forceinline__ unsigned short bf16r(float x) {
  unsigned u = __float_as_uint(x);
  return (unsigned short)((u + 0x7FFFu + ((u >> 16) & 1u)) >> 16);
}
__device__ __forceinline__ void bsplit(float v, unsigned short& hi, unsigned short& lo) {
  hi = bf16r(v);
  float hf = __uint_as_float((unsigned)hi << 16);
  lo = bf16r(v - hf);
}

// A-fragment pack: Af[tap][mt][hl][lane] (uint4 = 8 bf16). HW-verified r2.
// mfma_f32_16x16x32_bf16 A layout: row m = lane&15, k = (lane>>4)*8 + j.
// m = f*4 + gate; oc = gate*21 + f (Keras i,f,c,o).
// hl=0: bf16(w); hl=1: bf16(w - bf16(w)). x weights duplicated at ci 27..29.
__global__ void prep_kernel(const float* __restrict__ k,
                            const float* __restrict__ rk,
                            const float* __restrict__ bias,
                            unsigned short* __restrict__ Af,
                            float* __restrict__ bias4) {
  int i = blockIdx.x * 256 + threadIdx.x;
  if (i < NTAP * MT_ * 2 * 64 * 8) {
    int j    = i & 7;
    int lane = (i >> 3) & 63;
    int hl   = (i >> 9) & 1;
    int mtp  = i >> 10;          // tap*MT_ + mt
    int mt   = mtp % MT_;
    int tap  = mtp / MT_;
    int m    = mt * 16 + (lane & 15);
    int ci   = (lane >> 4) * 8 + j;
    int f    = m >> 2, gate = m & 3;
    float w = 0.0f;
    if (f < F_) {
      int oc = gate * F_ + f;
      if (ci < F_)                  w = rk[(tap * F_ + ci) * F4_ + oc];        // h
      else if (ci >= 24 && ci < 27) w = k[(tap * C_ + (ci - 24)) * F4_ + oc];  // x_hi slot
      else if (ci >= 27 && ci < 30) w = k[(tap * C_ + (ci - 27)) * F4_ + oc];  // x_lo slot (dup wx)
    }
    unsigned short hb = bf16r(w);
    unsigned short outv;
    if (hl == 0) outv = hb;
    else {
      float hf = __uint_as_float((unsigned)hb << 16);
      outv = bf16r(w - hf);
    }
    Af[i] = outv;
  }
  if (i < 96) {   // bias4[f][gate], f padded to 24
    int f = i >> 2, gate = i & 3;
    bias4[i] = (f < F_) ? bias[gate * F_ + f] : 0.0f;
  }
}

// ---------------- packed-h 1-step kernel (hi-only B, affine LDS) ----------------
// grid (6,21,16), block 768 (12 waves): wvm = wv>>2 (0..2) owns m-tiles
// {2wvm,2wvm+1}; wvn = wv&3 owns rows {2wvn,2wvn+1} (4 n-tiles).
// Round 12: LINEAR LDS rows of 80B (no XOR swizzle). pos-stride 80B = 20 banks
// -> every 16-lane k-group is exactly 2-way bank-aliased (free, m136), and the
// B-read address is affine: rb[nt] + (ky*TPX+kx)*80. rb computed once before
// the tap loop -> the in-loop VALU addressing (~280 ops) collapses to 4
// uniform adds per tap. Same values/order as r9-r11 -> bitwise-identical.
__global__ void __launch_bounds__(768, 6) step_kernel_p(
    const float* __restrict__ x,        // (B,T,H,W,C) fp32
    const uint4* __restrict__ Af,       // [9][6][2][64] uint4
    const float* __restrict__ bias4,    // [24][4]
    const uint4* __restrict__ g_in,     // h bf16-hi plane (prev step)
    uint4* __restrict__ g_out,          // h bf16-hi plane (this step)
    float* __restrict__ c_buf,          // (B,21,HW) fp32 in-place
    const float* __restrict__ mask,     // (H,W,1)
    float* __restrict__ out,            // (B,H,W,21) fp32, last step only
    int t, int first, int last) {
  __shared__ uint4 tileQ[NPOS * 5];     // 27200 B, linear [pos][slot]
  __shared__ uint4 bounceQ[768];        // 12288 B (disjoint -> no post-MFMA barrier)
  unsigned char* tile = (unsigned char*)tileQ;
  unsigned short* bh16 = (unsigned short*)bounceQ;   // [256][24] bf16-hi bounce

  int b   = blockIdx.z;
  int by0 = blockIdx.y * TSY;
  int bx0 = blockIdx.x * TSX;
  int tid = threadIdx.x;

  // ---- stage tile: slots 0..2 = h groups (raw 16B copies); slot 3 = x hi+lo ----
  // Writes at pos*80 + slot*16: consecutive pos -> 20-bank stride, 2-way free.
  for (int i = tid; i < 4 * NPOS; i += 768) {
    int slot = i / NPOS;
    int pos  = i - slot * NPOS;
    int py = pos / TPX, px = pos - py * TPX;
    int gy = by0 - 1 + py, gx = bx0 - 1 + px;
    bool inb = (unsigned)gy < (unsigned)H_ && (unsigned)gx < (unsigned)W_;
    if (slot < 3) {
      uint4 v = {0u, 0u, 0u, 0u};
      if (!first && inb)
        v = g_in[(size_t)(b * 3 + slot) * HW_ + gy * W_ + gx];
      *(uint4*)&tile[pos * ROWB5 + slot * 16] = v;
    } else {
      float x0 = 0.f, x1 = 0.f, x2 = 0.f;
      if (inb) {
        const float* xp = x + (((size_t)(b * T_ + t) * H_ + gy) * W_ + gx) * C_;
        x0 = xp[0]; x1 = xp[1]; x2 = xp[2];
      }
      unsigned short h0, h1, h2, l0, l1, l2;
      bsplit(x0, h0, l0); bsplit(x1, h1, l1); bsplit(x2, h2, l2);
      // k-slots 24..31 within this 16B: [x0h,x1h,x2h, x0l,x1l,x2l, 0,0]
      uint4 v;
      v.x = (unsigned)h0 | ((unsigned)h1 << 16);
      v.y = (unsigned)h2 | ((unsigned)l0 << 16);
      v.z = (unsigned)l1 | ((unsigned)l2 << 16);
      v.w = 0u;
      *(uint4*)&tile[pos * ROWB5 + 3 * 16] = v;
    }
  }
  __syncthreads();

  int lane = tid & 63;
  int wv   = tid >> 6;     // 0..11
  int wvm  = wv >> 2;      // m-group 0..2 -> m-tiles {2wvm, 2wvm+1}
  int wvn  = wv & 3;       // row pair 0..3 -> rows {2wvn, 2wvn+1}
  int ln15 = lane & 15;
  int lg   = lane >> 4;

  f32x4 acc[2][4];
#pragma unroll
  for (int mt = 0; mt < 2; ++mt)
#pragma unroll
    for (int nt = 0; nt < 4; ++nt)
      acc[mt][nt] = (f32x4){0.f, 0.f, 0.f, 0.f};

  // Per-nt LDS byte bases (loop-invariant): affine addressing, computed once.
  int rb[4];
#pragma unroll
  for (int nt = 0; nt < 4; ++nt) {
    int pos0 = (wvn * 2 + (nt >> 1)) * TPX + (nt & 1) * 16 + ln15;
    rb[nt] = pos0 * ROWB5 + lg * 16;
  }

#pragma unroll 1
  for (int tap = 0; tap < NTAP; ++tap) {
    int ky = tap / 3;
    int kx = tap - 3 * ky;
    int toff = (ky * TPX + kx) * ROWB5;   // wave-uniform tap offset

    const uint4* ap0 = Af + (size_t)((tap * MT_ + wvm * 2 + 0) * 2) * 64 + lane;
    const uint4* ap1 = Af + (size_t)((tap * MT_ + wvm * 2 + 1) * 2) * 64 + lane;
    bf16x8 ah0 = __builtin_bit_cast(bf16x8, ap0[0]);
    bf16x8 al0 = __builtin_bit_cast(bf16x8, ap0[64]);
    bf16x8 ah1 = __builtin_bit_cast(bf16x8, ap1[0]);
    bf16x8 al1 = __builtin_bit_cast(bf16x8, ap1[64]);

#pragma unroll
    for (int nt = 0; nt < 4; ++nt) {
      uint4 hv = *(const uint4*)&tile[rb[nt] + toff];
      bf16x8 bh = __builtin_bit_cast(bf16x8, hv);
      acc[0][nt] = __builtin_amdgcn_mfma_f32_16x16x32_bf16(ah0, bh, acc[0][nt], 0, 0, 0);
      acc[0][nt] = __builtin_amdgcn_mfma_f32_16x16x32_bf16(al0, bh, acc[0][nt], 0, 0, 0);
      acc[1][nt] = __builtin_amdgcn_mfma_f32_16x16x32_bf16(ah1, bh, acc[1][nt], 0, 0, 0);
      acc[1][nt] = __builtin_amdgcn_mfma_f32_16x16x32_bf16(al1, bh, acc[1][nt], 0, 0, 0);
    }
  }

  // NO barrier here: bounce is disjoint from tile; each wave proceeds into its
  // epilogue immediately, overlapping other waves' MFMA phase.

  // ---- lane-local LSTM epilogue; h -> bounce LDS as bf16-hi ----
#pragma unroll
  for (int mt = 0; mt < 2; ++mt) {
    int f = (wvm * 2 + mt) * 4 + lg;    // 0..23 (21..23 -> exact zero h)
    float4 bb = ((const float4*)bias4)[f];
#pragma unroll
    for (int nt = 0; nt < 4; ++nt) {
      int py = wvn * 2 + (nt >> 1);
      int px = (nt & 1) * 16 + ln15;
      int gy = by0 + py, gx = bx0 + px;
      if (gy < H_ && gx < W_) {
        int    pixL = py * TSX + px;
        size_t gpix = (size_t)gy * W_ + gx;
        float zi = acc[mt][nt][0] + bb.x;
        float zf = acc[mt][nt][1] + bb.y;
        float zc = acc[mt][nt][2] + bb.z;
        float zo = acc[mt][nt][3] + bb.w;
        float ig = hsig(zi);
        float fg = hsig(zf);
        float gg = fast_tanh(zc);
        float og = hsig(zo);
        float cp = (first || f >= F_) ? 0.0f
                                      : c_buf[((size_t)b * F_ + f) * HW_ + gpix];
        float cn = fg * cp + ig * gg;
        float hn = og * fast_tanh(cn);
        if (f < F_ && !last) c_buf[((size_t)b * F_ + f) * HW_ + gpix] = cn;
        if (last) {
          if (f < F_)
            out[((size_t)(b * H_ + gy) * W_ + gx) * F_ + f] = hn * mask[gpix];
        } else {
          bh16[pixL * 24 + f] = bf16r(hn);
        }
      }
    }
  }

  if (last) return;
  __syncthreads();

  // ---- pack bounce -> g_out (coalesced 16B stores), 1 iter/thread ----
  for (int i = tid; i < 256 * 3; i += 768) {
    int g    = i >> 8;
    int pixL = i & 255;
    int py = pixL >> 5, px = pixL & 31;
    int gy = by0 + py, gx = bx0 + px;
    if (gy < H_ && gx < W_) {
      uint4 v = *(const uint4*)(bh16 + pixL * 24 + g * 8);
      g_out[(size_t)(b * 3 + g) * HW_ + (size_t)gy * W_ + gx] = v;
    }
  }
}

// ---------------- fallback path (round-2 proven structure, ~78 MB ws) ----------------
// Consumes the same Af (x_lo k-slots stage as zero; its ah*bl term recovers x_lo).
__global__ void __launch_bounds__(256, 3) step_kernel_f(
    const float* __restrict__ x,
    const uint4* __restrict__ Af,
    const float* __restrict__ bias4,
    const float* __restrict__ h_in,     // (B,F,HW) fp32
    float* __restrict__ h_out,          // (B,F,HW) fp32
    float* __restrict__ c_buf,
    const float* __restrict__ mask,
    float* __restrict__ out,
    int t, int first, int last) {
  __shared__ uint4 tileQ[NPOS * 8];
  unsigned char* tile = (unsigned char*)tileQ;

  int b   = blockIdx.z;
  int by0 = blockIdx.y * TSY;
  int bx0 = blockIdx.x * TSX;
  int tid = threadIdx.x;

  for (int i = tid; i < 32 * NPOS; i += 256) {
    int ci  = i / NPOS;
    int pos = i - ci * NPOS;
    int py = pos / TPX, px = pos - py * TPX;
    int gy = by0 - 1 + py, gx = bx0 - 1 + px;
    float v = 0.0f;
    if ((unsigned)gy < (unsigned)H_ && (unsigned)gx < (unsigned)W_) {
      if (ci < F_) {
        if (!first) v = h_in[(size_t)(b * F_ + ci) * HW_ + gy * W_ + gx];
      } else if (ci >= 24 && ci < 27) {
        v = x[(((size_t)(b * T_ + t) * H_ + gy) * W_ + gx) * C_ + (ci - 24)];
      }
    }
    unsigned short hb, lb;
    bsplit(v, hb, lb);
    int g  = ci >> 3, e = ci & 7, sw = pos & 7;
    *(unsigned short*)&tile[pos * ROWBF + (((g * 2 + 0) ^ sw) * 16) + e * 2] = hb;
    *(unsigned short*)&tile[pos * ROWBF + (((g * 2 + 1) ^ sw) * 16) + e * 2] = lb;
  }
  __syncthreads();

  int lane = tid & 63;
  int wv   = tid >> 6;
  int ln15 = lane & 15;
  int lg   = lane >> 4;

  f32x4 acc[MT_][4];
#pragma unroll
  for (int mt = 0; mt < MT_; ++mt)
#pragma unroll
    for (int nt = 0; nt < 4; ++nt)
      acc[mt][nt] = (f32x4){0.f, 0.f, 0.f, 0.f};

#pragma unroll 1
  for (int tap = 0; tap < NTAP; ++tap) {
    int ky = tap / 3;
    int kx = tap - 3 * ky;

    bf16x8 bh[4], bl[4];
#pragma unroll
    for (int nt = 0; nt < 4; ++nt) {
      int pos = (wv * 2 + (nt >> 1) + ky) * TPX + (nt & 1) * 16 + ln15 + kx;
      int sw  = pos & 7;
      uint4 hv = *(const uint4*)&tile[pos * ROWBF + (((lg * 2 + 0) ^ sw) * 16)];
      uint4 lv = *(const uint4*)&tile[pos * ROWBF + (((lg * 2 + 1) ^ sw) * 16)];
      bh[nt] = __builtin_bit_cast(bf16x8, hv);
      bl[nt] = __builtin_bit_cast(bf16x8, lv);
    }

#pragma unroll
    for (int mt = 0; mt < MT_; ++mt) {
      const uint4* ap = Af + (size_t)((tap * MT_ + mt) * 2) * 64 + lane;
      bf16x8 ah = __builtin_bit_cast(bf16x8, ap[0]);
      bf16x8 al = __builtin_bit_cast(bf16x8, ap[64]);
#pragma unroll
      for (int nt = 0; nt < 4; ++nt) {
        acc[mt][nt] = __builtin_amdgcn_mfma_f32_16x16x32_bf16(ah, bh[nt], acc[mt][nt], 0, 0, 0);
        acc[mt][nt] = __builtin_amdgcn_mfma_f32_16x16x32_bf16(ah, bl[nt], acc[mt][nt], 0, 0, 0);
        acc[mt][nt] = __builtin_amdgcn_mfma_f32_16x16x32_bf16(al, bh[nt], acc[mt][nt], 0, 0, 0);
      }
    }
  }

#pragma unroll
  for (int mt = 0; mt < MT_; ++mt) {
    int f = mt * 4 + lg;
    if (f < F_) {
      float4 bb = ((const float4*)bias4)[f];
#pragma unroll
      for (int nt = 0; nt < 4; ++nt) {
        int gy = by0 + wv * 2 + (nt >> 1);
        int gx = bx0 + (nt & 1) * 16 + ln15;
        if (gy < H_ && gx < W_) {
          size_t idx = ((size_t)b * F_ + f) * HW_ + (size_t)gy * W_ + gx;
          float zi = acc[mt][nt][0] + bb.x;
          float zf = acc[mt][nt][1] + bb.y;
          float zc = acc[mt][nt][2] + bb.z;
          float zo = acc[mt][nt][3] + bb.w;
          float ig = hsig(zi);
          float fg = hsig(zf);
          float gg = fast_tanh(zc);
          float og = hsig(zo);
          float cp = first ? 0.0f : c_buf[idx];
          float cn = fg * cp + ig * gg;
          float hn = og * fast_tanh(cn);
          c_buf[idx] = cn;
          if (!last) h_out[idx] = hn;
          else {
            out[((size_t)(b * H_ + gy) * W_ + gx) * F_ + f] =
                hn * mask[(size_t)gy * W_ + gx];
          }
        }
      }
    }
  }
}

extern "C" void kernel_launch(void* const* d_in, const int* in_sizes, int n_in,
                              void* d_out, int out_size, void* d_ws, size_t ws_size,
                              hipStream_t stream) {
  const float* x  = (const float*)d_in[0];
  const float* k  = (const float*)d_in[1];
  const float* rk = (const float*)d_in[2];
  const float* bs = (const float*)d_in[3];
  const float* mk = (const float*)d_in[4];
  float* outF = (float*)d_out;

  char* ws = (char*)d_ws;
  unsigned short* Af = (unsigned short*)ws;          // 110592 B
  float* bias4 = (float*)(ws + 110592);              // 384 B
  size_t off = (size_t)((110592 + 384 + 255) & ~255);
  size_t HWF = (size_t)B_ * H_ * W_ * F_;

  prep_kernel<<<dim3((NTAP * MT_ * 2 * 64 * 8 + 255) / 256), 256, 0, stream>>>(
      k, rk, bs, Af, bias4);

  dim3 grid((W_ + TSX - 1) / TSX, (H_ + TSY - 1) / TSY, B_);  // (6, 21, 16)

  size_t need_packed = off + (size_t)2 * GH_ * 16 + HWF * 4;  // ~84 MB

  if (ws_size >= need_packed) {
    // packed-h path: ghA/ghB = bf16-hi h planes, c fp32
    uint4* ghA = (uint4*)(ws + off);
    uint4* ghB = ghA + GH_;
    float* cB  = (float*)(ghB + GH_);
    for (int t = 0; t < T_; ++t) {
      const uint4* gin = (t & 1) ? ghB : ghA;
      uint4* gout      = (t & 1) ? ghA : ghB;
      step_kernel_p<<<grid, 768, 0, stream>>>(x, (const uint4*)Af, bias4, gin, gout,
                                              cB, mk, outF, t,
                                              (t == 0) ? 1 : 0, (t == T_ - 1) ? 1 : 0);
    }
  } else {
    // fallback (round-2 proven): fp32 h ping-pong via ws + outF, ~78.4 MB
    float* hA = (float*)(ws + off);
    float* cB = hA + HWF;
    for (int t = 0; t < T_; ++t) {
      const float* hi = (t & 1) ? hA : outF;
      float* ho       = (t & 1) ? outF : hA;
      step_kernel_f<<<grid, 256, 0, stream>>>(x, (const uint4*)Af, bias4, hi, ho,
                                              cB, mk, outF, t,
                                              (t == 0) ? 1 : 0, (t == T_ - 1) ? 1 : 0);
    }
  }
}